// Round 1
// baseline (16.197 us; speedup 1.0000x reference)
//
#include <hip/hip_runtime.h>

#define NQ 16

__global__ __launch_bounds__(256) void qfc_kernel(
    const float* __restrict__ x,
    const float* __restrict__ theta,
    const float* __restrict__ w,
    const float* __restrict__ bias,
    float* __restrict__ out,
    int ntok)
{
    int t = blockIdx.x * blockDim.x + threadIdx.x;
    if (t >= ntok) return;

    // ct[q] = cos(theta[q]) * w[q]  — tiny, L1/L2 broadcast across all waves
    float ct[NQ];
#pragma unroll
    for (int q = 0; q < NQ; ++q) ct[q] = __cosf(theta[q]) * w[q];

    const float4* xv = reinterpret_cast<const float4*>(x) + (size_t)t * (NQ / 4);
    float acc = bias[0];
#pragma unroll
    for (int m = 0; m < 4; ++m) {
        float4 v = xv[m];
        acc += __cosf(v.x) * ct[4 * m + 0];
        acc += __cosf(v.y) * ct[4 * m + 1];
        acc += __cosf(v.z) * ct[4 * m + 2];
        acc += __cosf(v.w) * ct[4 * m + 3];
    }
    out[t] = acc;
}

extern "C" void kernel_launch(void* const* d_in, const int* in_sizes, int n_in,
                              void* d_out, int out_size, void* d_ws, size_t ws_size,
                              hipStream_t stream) {
    const float* x     = (const float*)d_in[0];  // [B, S, 16]
    const float* theta = (const float*)d_in[1];  // [16]
    const float* w     = (const float*)d_in[2];  // [1, 16]
    const float* bias  = (const float*)d_in[3];  // [1]
    float* out = (float*)d_out;                  // [B, S, 1] flat

    int ntok = out_size;                         // 128 * 8192 = 1,048,576
    int block = 256;
    int grid = (ntok + block - 1) / block;       // 4096 blocks
    qfc_kernel<<<grid, block, 0, stream>>>(x, theta, w, bias, out, ntok);
}